// Round 19
// baseline (289.394 us; speedup 1.0000x reference)
//
#include <hip/hip_runtime.h>
#include <cmath>

#define TOK   8192
#define RNK   256
#define NEXP  16
#define NREF  64
#define DM    1024
#define KTOT  4096

#define Y_OFF  0
#define IR_OFF (TOK*DM)
#define W_OFF  (IR_OFF + TOK*2)
#define ID_OFF (W_OFF + TOK*NEXP)

#define EBT_BYTES ((size_t)DM * KTOT * 2)         // 8 MB
#define XF_BYTES  ((size_t)TOK * RNK * 4)         // 8 MB
#define XH_BYTES  ((size_t)TOK * RNK * 2)         // 4 MB
#define GT_BYTES  ((size_t)NEXP * NREF * RNK * 2) // 512 KB
#define S_BYTES   ((size_t)TOK * NREF * 4)        // 2 MB (layout slot, unused)
#define G64_BYTES ((size_t)NREF * KTOT * 8)       // 2 MB
#define SR_BYTES  ((size_t)TOK * NREF * 8)        // 4 MB
#define WS_FULL   (EBT_BYTES + XF_BYTES + 2*XH_BYTES + 2*GT_BYTES + S_BYTES + G64_BYTES + SR_BYTES)

typedef __attribute__((ext_vector_type(8))) short short8;
typedef __attribute__((ext_vector_type(4))) float f32x4;
typedef const __attribute__((address_space(1))) void* gptr_t;
typedef __attribute__((address_space(3))) void* lptr_t;

__device__ inline unsigned short f2bf(float f) {    // RNE float->bf16
    unsigned int u = __float_as_uint(f);
    return (unsigned short)((u + 0x7fffu + ((u >> 16) & 1u)) >> 16);
}
__device__ inline float bf2f(unsigned short h) {
    return __uint_as_float(((unsigned int)h) << 16);
}
__device__ inline void split2(float v, unsigned short& h, unsigned short& l) {
    h = f2bf(v);
    l = f2bf(v - bf2f(h));
}
__device__ inline unsigned long long pack4(unsigned short a, unsigned short b,
                                           unsigned short c, unsigned short d) {
    return (unsigned long long)a | ((unsigned long long)b << 16)
         | ((unsigned long long)c << 32) | ((unsigned long long)d << 48);
}

// ---------- top-2 across a 64-lane wave, lax.top_k tie semantics ----------
__device__ inline void top2_64(double v, int idx, int& i0, int& i1) {
    double bv = v; int bi = idx;
    #pragma unroll
    for (int m = 1; m < 64; m <<= 1) {
        double ov = __shfl_xor(bv, m, 64);
        int    oi = __shfl_xor(bi, m, 64);
        if (ov > bv || (ov == bv && oi < bi)) { bv = ov; bi = oi; }
    }
    i0 = bi;
    double v2 = (idx == i0) ? -INFINITY : v;
    double bv2 = v2; int bi2 = idx;
    #pragma unroll
    for (int m = 1; m < 64; m <<= 1) {
        double ov = __shfl_xor(bv2, m, 64);
        int    oi = __shfl_xor(bi2, m, 64);
        if (ov > bv2 || (ov == bv2 && oi < bi2)) { bv2 = ov; bi2 = oi; }
    }
    i1 = bi2;
}

// ======== PREP: sr_fp64 (0..1023) | e_transpose (1024..2047) | g_fp64 ======
__global__ __launch_bounds__(256) void prep(
    const float* __restrict__ x, const float* __restrict__ Wr,
    const float* __restrict__ E, const float* __restrict__ Wd,
    double* __restrict__ Sr, unsigned short* __restrict__ Ebt,
    double* __restrict__ G64t,
    unsigned short* __restrict__ Gth, unsigned short* __restrict__ Gtl)
{
    __shared__ __align__(16) float lds_raw[64 * 68];
    const int bid = blockIdx.x;
    const int tid = threadIdx.x;
    const int w = tid >> 6, n = tid & 63;

    if (bid < 1024) {
        // ---- sr_fp64: 8 tokens/block (2 per thread) ----
        float* wt2 = lds_raw;                // [64][68], wt2[n][d]
        const int t0 = bid * 8;
        double acc[2] = {0.0, 0.0};
        const float* xr0 = x + (size_t)(t0 + w * 2 + 0) * RNK;
        const float* xr1 = x + (size_t)(t0 + w * 2 + 1) * RNK;
        for (int d0 = 0; d0 < RNK; d0 += 64) {
            __syncthreads();
            #pragma unroll
            for (int rep = 0; rep < 4; ++rep) {
                int f = rep * 256 + tid;
                int nn = f >> 4, dgw = (f & 15) << 2;
                float4 v = *(const float4*)(Wr + (size_t)nn * RNK + d0 + dgw);
                *(float4*)&wt2[nn * 68 + dgw] = v;
            }
            __syncthreads();
            #pragma unroll
            for (int dg = 0; dg < 16; ++dg) {
                float4 e0 = *(const float4*)(xr0 + d0 + dg * 4);
                float4 e1 = *(const float4*)(xr1 + d0 + dg * 4);
                float4 w4 = *(const float4*)&wt2[n * 68 + dg * 4];
                #pragma unroll
                for (int j = 0; j < 4; ++j) {
                    double wv = (double)(&w4.x)[j];
                    acc[0] = fma((double)(&e0.x)[j], wv, acc[0]);
                    acc[1] = fma((double)(&e1.x)[j], wv, acc[1]);
                }
            }
        }
        #pragma unroll
        for (int i = 0; i < 2; ++i)
            Sr[(size_t)(t0 + w * 2 + i) * NREF + n] = acc[i];
    } else if (bid < 2048) {
        // ---- e_transpose ----
        const int id = bid - 1024;
        const int k0 = (id & 63) * 64, d0 = (id >> 6) * 64;
        #pragma unroll
        for (int rep = 0; rep < 4; ++rep) {
            int idx = rep * 256 + tid;
            int r = idx >> 4, c4 = (idx & 15) << 2;
            float4 v = *(const float4*)(E + (size_t)(k0 + r) * DM + d0 + c4);
            lds_raw[r * 68 + c4 + 0] = v.x; lds_raw[r * 68 + c4 + 1] = v.y;
            lds_raw[r * 68 + c4 + 2] = v.z; lds_raw[r * 68 + c4 + 3] = v.w;
        }
        __syncthreads();
        #pragma unroll
        for (int rep = 0; rep < 4; ++rep) {
            int idx = rep * 256 + tid;
            int dr = idx >> 4, kc4 = (idx & 15) << 2;
            *(unsigned long long*)&Ebt[(size_t)(d0 + dr) * KTOT + k0 + kc4] =
                pack4(f2bf(lds_raw[(kc4 + 0) * 68 + dr]),
                      f2bf(lds_raw[(kc4 + 1) * 68 + dr]),
                      f2bf(lds_raw[(kc4 + 2) * 68 + dr]),
                      f2bf(lds_raw[(kc4 + 3) * 68 + dr]));
        }
    } else {
        // ---- g_fp64: 4 k-rows/block (1 per wave) ----
        float* wt2 = lds_raw;                // [64][68], wt2[n][d]
        const int k = (bid - 2048) * 4 + w;
        double acc = 0.0;
        const float* erow = E + (size_t)k * DM;
        for (int d0 = 0; d0 < DM; d0 += 64) {
            __syncthreads();
            #pragma unroll
            for (int rep = 0; rep < 4; ++rep) {
                int f = rep * 256 + tid;
                int nn = f >> 4, dgw = (f & 15) << 2;
                float4 v = *(const float4*)(Wd + (size_t)nn * DM + d0 + dgw);
                *(float4*)&wt2[nn * 68 + dgw] = v;
            }
            __syncthreads();
            #pragma unroll
            for (int dg = 0; dg < 16; ++dg) {
                float4 e0 = *(const float4*)(erow + d0 + dg * 4);
                float4 w4 = *(const float4*)&wt2[n * 68 + dg * 4];
                #pragma unroll
                for (int j = 0; j < 4; ++j)
                    acc = fma((double)(&e0.x)[j], (double)(&w4.x)[j], acc);
            }
        }
        G64t[(size_t)n * KTOT + k] = acc;
        float gf = (float)acc;
        unsigned short h, lo;
        split2(gf, h, lo);
        const int e = k >> 8, r = k & 255;
        Gth[((size_t)(e * NREF + n)) * RNK + r] = h;
        Gtl[((size_t)(e * NREF + n)) * RNK + r] = lo;
    }
}

// ======== K1A: token phase, 4 tokens/block -> 2048 blocks (8/CU) ==========
// Per-token FP sequence identical to r18's k1s token loop. xprime stored
// (k1b reloads it for the rescore). scores_e uses 4 ILP accumulators
// (regrouping only; reference computes scores_e in fp32 anyway).
__global__ __launch_bounds__(256) void k1a(
    const double* __restrict__ Sr, const float* __restrict__ x,
    const float* __restrict__ We, const float* __restrict__ reflect_r,
    float* __restrict__ xprime,
    unsigned short* __restrict__ Xh, unsigned short* __restrict__ Xl,
    float* __restrict__ out_ir, float* __restrict__ out_w)
{
    __shared__ float we_lds[16 * 260];   // 16.6 KB
    __shared__ float xs[4][260];
    const int tid = threadIdx.x;
    const int w = tid >> 6, lane = tid & 63;
    const int t = blockIdx.x * 4 + w;

    #pragma unroll
    for (int rep = 0; rep < 4; ++rep) {
        int f = rep * 256 + tid;
        int row = f >> 6, c4 = (f & 63) << 2;
        float4 v = *(const float4*)(We + (size_t)row * RNK + c4);
        *(float4*)&we_lds[row * 260 + c4] = v;
    }
    __syncthreads();

    float4 xv = *(const float4*)(x + (size_t)t * RNK + lane * 4);
    double s = Sr[(size_t)t * NREF + lane];
    int i0, i1;
    top2_64(s, lane, i0, i1);

    #pragma unroll
    for (int rr = 0; rr < 2; ++rr) {
        int idx = rr ? i1 : i0;
        float4 vv = *(const float4*)(reflect_r + (size_t)idx * RNK + lane * 4);
        float sv = vv.x * xv.x + vv.y * xv.y + vv.z * xv.z + vv.w * xv.w;
        float vn = vv.x * vv.x + vv.y * vv.y + vv.z * vv.z + vv.w * vv.w;
        #pragma unroll
        for (int m = 1; m < 64; m <<= 1) {
            sv += __shfl_xor(sv, m, 64);
            vn += __shfl_xor(vn, m, 64);
        }
        float coef = 2.0f * sv / (vn + 1e-8f);
        xv.x -= coef * vv.x; xv.y -= coef * vv.y;
        xv.z -= coef * vv.z; xv.w -= coef * vv.w;
    }

    *(float4*)&xs[w][lane * 4] = xv;
    *(float4*)(xprime + (size_t)t * RNK + lane * 4) = xv;

    const int n16 = lane & 15;
    double se = 0.0;
    {
        const float* werow = &we_lds[n16 * 260];
        double s0 = 0.0, s1 = 0.0, s2 = 0.0, s3 = 0.0;   // 4-way ILP
        #pragma unroll 4
        for (int r4 = 0; r4 < RNK / 4; r4 += 4) {
            #pragma unroll
            for (int u = 0; u < 4; ++u) {
                float4 xr = *(const float4*)(&xs[w][(r4 + u) * 4]);
                float4 wf = *(const float4*)(werow + (r4 + u) * 4);
                double p = (double)xr.x * wf.x + (double)xr.y * wf.y
                         + (double)xr.z * wf.z + (double)xr.w * wf.w;
                if (u == 0) s0 += p; else if (u == 1) s1 += p;
                else if (u == 2) s2 += p; else s3 += p;
            }
        }
        se = (s0 + s1) + (s2 + s3);
    }
    float sef = (float)se;
    float mx = sef;
    #pragma unroll
    for (int m = 1; m < 16; m <<= 1) mx = fmaxf(mx, __shfl_xor(mx, m, 64));
    float ex = expf(sef - mx);
    float sm = ex;
    #pragma unroll
    for (int m = 1; m < 16; m <<= 1) sm += __shfl_xor(sm, m, 64);
    float wgt = ex / sm;

    if (lane < NEXP) out_w[(size_t)t * NEXP + lane] = wgt;
    if (lane == 0) {
        out_ir[(size_t)t * 2 + 0] = (float)i0;
        out_ir[(size_t)t * 2 + 1] = (float)i1;
    }

    unsigned short hx, lx, hy, ly, hz, lz, hw, lw;
    split2(xv.x, hx, lx); split2(xv.y, hy, ly);
    split2(xv.z, hz, lz); split2(xv.w, hw, lw);
    *(unsigned long long*)&Xh[(size_t)t * RNK + lane * 4] = pack4(hx, hy, hz, hw);
    *(unsigned long long*)&Xl[(size_t)t * RNK + lane * 4] = pack4(lx, ly, lz, lw);
}

// ======== K1B: s_mfma + gap-gated refine, 16 tokens/block ==================
// xs/wsh reloaded from xprime/out_w (identical fp32 values -> bit-identical
// S, gate decisions, and rescore results).
__global__ __launch_bounds__(512, 4) void k1b(
    const float* __restrict__ xprime, const float* __restrict__ out_w,
    const unsigned short* __restrict__ Gth, const unsigned short* __restrict__ Gtl,
    const double* __restrict__ G64t,
    const unsigned short* __restrict__ Xh, const unsigned short* __restrict__ Xl,
    float* __restrict__ out_id)
{
    __shared__ __align__(16) float red[4 * 16 * 64];   // 16 KB
    __shared__ float xs[16][260];                      // 16.6 KB
    __shared__ float wsh[16][16];
    __shared__ float sfin[16][64];
    const int tid = threadIdx.x;
    const int w = tid >> 6, lane = tid & 63;   // w = 0..7
    const int t0 = blockIdx.x * 16;

    // stage xs (16 tokens x 256 f32) and wsh
    #pragma unroll
    for (int rep = 0; rep < 8; ++rep) {
        int f = rep * 512 + tid;
        int tok = f >> 6, c4 = (f & 63) << 2;
        *(float4*)&xs[tok][c4] =
            *(const float4*)(xprime + (size_t)(t0 + tok) * RNK + c4);
    }
    if (tid < 256)
        wsh[tid >> 4][tid & 15] = out_w[(size_t)(t0 + (tid >> 4)) * NEXP + (tid & 15)];
    __syncthreads();

    // ---- s-body: 8 waves x 2 experts each; A-frags from global ----
    const int l = lane;
    short8 ah[8], al[8];
    {
        const size_t abase = (size_t)(t0 + (l & 15)) * RNK + (l >> 4) * 8;
        #pragma unroll
        for (int ks = 0; ks < 8; ++ks) {
            ah[ks] = *(const short8*)&Xh[abase + ks * 32];
            al[ks] = *(const short8*)&Xl[abase + ks * 32];
        }
    }

    f32x4 Sacc[4] = {};
    #pragma unroll
    for (int ei = 0; ei < 2; ++ei) {
        const int e = w * 2 + ei;
        f32x4 acc[4] = {};
        #pragma unroll
        for (int ks = 0; ks < 8; ++ks) {
            #pragma unroll
            for (int nn = 0; nn < 4; ++nn) {
                size_t gbase = ((size_t)(e * NREF + nn * 16 + (l & 15))) * RNK
                             + ks * 32 + (l >> 4) * 8;
                short8 bh = *(const short8*)&Gth[gbase];
                short8 bl = *(const short8*)&Gtl[gbase];
                acc[nn] = __builtin_amdgcn_mfma_f32_16x16x32_bf16(al[ks], bh, acc[nn], 0, 0, 0);
                acc[nn] = __builtin_amdgcn_mfma_f32_16x16x32_bf16(ah[ks], bl, acc[nn], 0, 0, 0);
                acc[nn] = __builtin_amdgcn_mfma_f32_16x16x32_bf16(ah[ks], bh, acc[nn], 0, 0, 0);
            }
        }
        #pragma unroll
        for (int j = 0; j < 4; ++j) {
            float wv = wsh[(l >> 4) * 4 + j][e];
            #pragma unroll
            for (int nn = 0; nn < 4; ++nn) Sacc[nn][j] += wv * acc[nn][j];
        }
    }
    // two-phase reduction into red[4][16][64]
    if (w < 4) {
        #pragma unroll
        for (int nn = 0; nn < 4; ++nn)
            #pragma unroll
            for (int j = 0; j < 4; ++j)
                red[(w * 16 + (l >> 4) * 4 + j) * 64 + nn * 16 + (l & 15)] = Sacc[nn][j];
    }
    __syncthreads();
    if (w >= 4) {
        #pragma unroll
        for (int nn = 0; nn < 4; ++nn)
            #pragma unroll
            for (int j = 0; j < 4; ++j)
                red[((w - 4) * 16 + (l >> 4) * 4 + j) * 64 + nn * 16 + (l & 15)] += Sacc[nn][j];
    }
    __syncthreads();
    for (int i = tid; i < 16 * 64; i += 512) {
        int tt = i >> 6, nn = i & 63;
        float sv = red[(0 * 16 + tt) * 64 + nn] + red[(1 * 16 + tt) * 64 + nn]
                 + red[(2 * 16 + tt) * 64 + nn] + red[(3 * 16 + tt) * 64 + nn];
        sfin[tt][nn] = sv;
    }
    __syncthreads();

    // ---- gap-gated refine: wave w handles tokens 2w, 2w+1 ----
    const float TAU = 1e-3f;   // >> S error (~3e-5)
    for (int ti = 0; ti < 2; ++ti) {
        const int tloc = w * 2 + ti;
        const int t = t0 + tloc;

        float cur = sfin[tloc][lane];
        int cand[4];
        float sval[4];
        #pragma unroll
        for (int c = 0; c < 4; ++c) {
            float bv = cur; int bi = lane;
            #pragma unroll
            for (int m = 1; m < 64; m <<= 1) {
                float ov = __shfl_xor(bv, m, 64);
                int   oi = __shfl_xor(bi, m, 64);
                if (ov > bv || (ov == bv && oi < bi)) { bv = ov; bi = oi; }
            }
            cand[c] = bi; sval[c] = bv;
            if (lane == bi) cur = -INFINITY;
        }

        int si0, si1;
        if (sval[0] - sval[1] > TAU && sval[1] - sval[2] > TAU) {
            si0 = cand[0]; si1 = cand[1];
        } else {
            double rs[4];
            #pragma unroll
            for (int c = 0; c < 4; ++c) {
                const double* grow = G64t + (size_t)cand[c] * KTOT;
                double acc = 0.0;
                #pragma unroll 4
                for (int i = 0; i < 64; ++i) {
                    int k = i * 64 + lane;
                    double a = (double)wsh[tloc][k >> 8] * (double)xs[tloc][k & 255];
                    acc = fma(a, grow[k], acc);
                }
                #pragma unroll
                for (int m = 1; m < 64; m <<= 1) acc += __shfl_xor(acc, m, 64);
                rs[c] = acc;
            }
            int b0 = 0;
            #pragma unroll
            for (int c = 1; c < 4; ++c)
                if (rs[c] > rs[b0] || (rs[c] == rs[b0] && cand[c] < cand[b0])) b0 = c;
            int b1 = (b0 == 0) ? 1 : 0;
            #pragma unroll
            for (int c = 0; c < 4; ++c) {
                if (c == b0) continue;
                if (rs[c] > rs[b1] || (rs[c] == rs[b1] && cand[c] < cand[b1])) b1 = c;
            }
            si0 = cand[b0]; si1 = cand[b1];
        }
        if (lane == 0) {
            out_id[(size_t)t * 2 + 0] = (float)si0;
            out_id[(size_t)t * 2 + 1] = (float)si1;
        }
    }
}

// ---------- K2 fused (round-8 structure, STANDALONE) ----------------------
__global__ __launch_bounds__(256) void k2_fused(
    const unsigned short* __restrict__ Xh,
    const unsigned short* __restrict__ Ebt,
    const float* __restrict__ wts,
    float* __restrict__ y)
{
    __shared__ unsigned short As[128 * 32];
    __shared__ unsigned short Bs[128 * 32];
    __shared__ float wt[NEXP * 132];
    const int tid = threadIdx.x;
    const int l = tid & 63, w = tid >> 6;
    const int wr = w >> 1, wc = w & 1;
    const int tm0 = blockIdx.y * 128, n0 = blockIdx.x * 128;
    const int lrow = l >> 2, s = l & 3, g = l >> 4;

    #pragma unroll
    for (int rep = 0; rep < 8; ++rep) {
        int f = rep * 256 + tid;
        int row = f >> 4, e = f & 15;
        wt[e * 132 + row] = wts[(size_t)(tm0 + row) * NEXP + e];
    }

    f32x4 acc[4][4] = {};

    for (int e = 0; e < NEXP; ++e) {
        f32x4 acc_e[4][4] = {};
        for (int kb8 = 0; kb8 < 8; ++kb8) {
            const int kb = e * 8 + kb8;
            __syncthreads();
            #pragma unroll
            for (int i = 0; i < 2; ++i) {
                int row = w * 32 + i * 16 + lrow;
                int sw = ((s ^ ((row >> 1) & 3)) << 4);
                const char* ga = (const char*)Xh
                    + ((size_t)(tm0 + row) * RNK + kb8 * 32) * 2 + sw;
                __builtin_amdgcn_global_load_lds((gptr_t)ga,
                    (lptr_t)&As[(w * 32 + i * 16) * 32], 16, 0, 0);
                const char* gb = (const char*)Ebt
                    + ((size_t)(n0 + row) * KTOT + kb * 32) * 2 + sw;
                __builtin_amdgcn_global_load_lds((gptr_t)gb,
                    (lptr_t)&Bs[(w * 32 + i * 16) * 32], 16, 0, 0);
            }
            __syncthreads();

            short8 af[4], bv[4];
            #pragma unroll
            for (int m = 0; m < 4; ++m) {
                int row = wr * 64 + m * 16 + (l & 15);
                af[m] = *(const short8*)&As[row * 32 + ((g ^ ((row >> 1) & 3)) << 3)];
            }
            #pragma unroll
            for (int nn = 0; nn < 4; ++nn) {
                int row = wc * 64 + nn * 16 + (l & 15);
                bv[nn] = *(const short8*)&Bs[row * 32 + ((g ^ ((row >> 1) & 3)) << 3)];
            }
            #pragma unroll
            for (int m = 0; m < 4; ++m)
                #pragma unroll
                for (int nn = 0; nn < 4; ++nn)
                    acc_e[m][nn] = __builtin_amdgcn_mfma_f32_16x16x32_bf16(
                        af[m], bv[nn], acc_e[m][nn], 0, 0, 0);
        }
        #pragma unroll
        for (int m = 0; m < 4; ++m) {
            int rowb = wr * 64 + m * 16 + (l >> 4) * 4;
            float4 wm = *(const float4*)&wt[e * 132 + rowb];
            #pragma unroll
            for (int nn = 0; nn < 4; ++nn) {
                #pragma unroll
                for (int j = 0; j < 4; ++j)
                    acc[m][nn][j] += (&wm.x)[j] * acc_e[m][nn][j];
            }
        }
    }

    #pragma unroll
    for (int m = 0; m < 4; ++m) {
        int rbase = tm0 + wr * 64 + m * 16 + (l >> 4) * 4;
        #pragma unroll
        for (int nn = 0; nn < 4; ++nn) {
            int c = n0 + wc * 64 + nn * 16 + (l & 15);
            #pragma unroll
            for (int j = 0; j < 4; ++j)
                y[(size_t)(rbase + j) * DM + c] = acc[m][nn][j];
        }
    }
}

// ---------- K3: read refined indices -> 2 reflections on y (in place) -----
__global__ __launch_bounds__(256) void k3_post(
    const float* __restrict__ out_id, const float* __restrict__ reflect_d,
    float* __restrict__ y)
{
    const int tid = threadIdx.x;
    const int w = tid >> 6, lane = tid & 63;
    const int t = blockIdx.x * 4 + w;

    float4 yv[4];
    #pragma unroll
    for (int c = 0; c < 4; ++c)
        yv[c] = *(const float4*)(y + (size_t)t * DM + lane * 16 + c * 4);

    const int i0 = (int)out_id[(size_t)t * 2 + 0];
    const int i1 = (int)out_id[(size_t)t * 2 + 1];

    #pragma unroll
    for (int rr = 0; rr < 2; ++rr) {
        int idx = rr ? i1 : i0;
        const float* vrow = reflect_d + (size_t)idx * DM + lane * 16;
        float sv = 0.f, vn = 0.f;
        float4 vv[4];
        #pragma unroll
        for (int c = 0; c < 4; ++c) {
            vv[c] = *(const float4*)(vrow + c * 4);
            sv += vv[c].x * yv[c].x + vv[c].y * yv[c].y
                + vv[c].z * yv[c].z + vv[c].w * yv[c].w;
            vn += vv[c].x * vv[c].x + vv[c].y * vv[c].y
                + vv[c].z * vv[c].z + vv[c].w * vv[c].w;
        }
        #pragma unroll
        for (int m = 1; m < 64; m <<= 1) {
            sv += __shfl_xor(sv, m, 64);
            vn += __shfl_xor(vn, m, 64);
        }
        float coef = 2.0f * sv / (vn + 1e-8f);
        #pragma unroll
        for (int c = 0; c < 4; ++c) {
            yv[c].x -= coef * vv[c].x; yv[c].y -= coef * vv[c].y;
            yv[c].z -= coef * vv[c].z; yv[c].w -= coef * vv[c].w;
        }
    }
    #pragma unroll
    for (int c = 0; c < 4; ++c)
        *(float4*)(y + (size_t)t * DM + lane * 16 + c * 4) = yv[c];
}

// ================= fallback path (ws too small), unchanged =================
__global__ __launch_bounds__(256) void k1_tokens(
    const float* __restrict__ x, const float* __restrict__ Wr,
    const float* __restrict__ We, const float* __restrict__ reflect_r,
    float* __restrict__ xprime, float* __restrict__ out_ir,
    float* __restrict__ out_w)
{
    __shared__ float xs[4][RNK];
    const int tid = threadIdx.x;
    const int w = tid >> 6, lane = tid & 63;
    const int t = blockIdx.x * 4 + w;

    float4 xv = *(const float4*)(x + (size_t)t * RNK + lane * 4);
    *(float4*)(&xs[w][lane * 4]) = xv;
    __syncthreads();

    double s = 0.0;
    {
        const float* wrow = Wr + (size_t)lane * RNK;
        for (int r4 = 0; r4 < RNK / 4; ++r4) {
            float4 xr = *(const float4*)(&xs[w][r4 * 4]);
            float4 wr = *(const float4*)(wrow + r4 * 4);
            s += (double)xr.x * wr.x + (double)xr.y * wr.y
               + (double)xr.z * wr.z + (double)xr.w * wr.w;
        }
    }
    int i0, i1;
    top2_64(s, lane, i0, i1);

    #pragma unroll
    for (int rr = 0; rr < 2; ++rr) {
        int idx = rr ? i1 : i0;
        float4 vv = *(const float4*)(reflect_r + (size_t)idx * RNK + lane * 4);
        float sv = vv.x * xv.x + vv.y * xv.y + vv.z * xv.z + vv.w * xv.w;
        float vn = vv.x * vv.x + vv.y * vv.y + vv.z * vv.z + vv.w * vv.w;
        #pragma unroll
        for (int m = 1; m < 64; m <<= 1) {
            sv += __shfl_xor(sv, m, 64);
            vn += __shfl_xor(vn, m, 64);
        }
        float coef = 2.0f * sv / (vn + 1e-8f);
        xv.x -= coef * vv.x; xv.y -= coef * vv.y;
        xv.z -= coef * vv.z; xv.w -= coef * vv.w;
    }
    __syncthreads();
    *(float4*)(&xs[w][lane * 4]) = xv;
    __syncthreads();

    *(float4*)(xprime + (size_t)t * RNK + lane * 4) = xv;

    const int n = lane & 15;
    double se = 0.0;
    {
        const float* werow = We + (size_t)n * RNK;
        for (int r4 = 0; r4 < RNK / 4; ++r4) {
            float4 xr = *(const float4*)(&xs[w][r4 * 4]);
            float4 wf = *(const float4*)(werow + r4 * 4);
            se += (double)xr.x * wf.x + (double)xr.y * wf.y
                + (double)xr.z * wf.z + (double)xr.w * wf.w;
        }
    }
    float sef = (float)se;
    float mx = sef;
    #pragma unroll
    for (int m = 1; m < 16; m <<= 1) mx = fmaxf(mx, __shfl_xor(mx, m, 64));
    float ex = expf(sef - mx);
    float sm = ex;
    #pragma unroll
    for (int m = 1; m < 16; m <<= 1) sm += __shfl_xor(sm, m, 64);
    float wgt = ex / sm;

    if (lane < NEXP) out_w[(size_t)t * NEXP + lane] = wgt;
    if (lane == 0) {
        out_ir[(size_t)t * 2 + 0] = (float)i0;
        out_ir[(size_t)t * 2 + 1] = (float)i1;
    }
}

__global__ __launch_bounds__(256) void k2_gemm(
    const float* __restrict__ xp, const float* __restrict__ wts,
    const float* __restrict__ E, float* __restrict__ y)
{
    __shared__ float As[16][132];
    __shared__ float Bs[16][132];
    const int tid = threadIdx.x;
    const int bn = blockIdx.x, bm = blockIdx.y;
    const int tm0 = bm * 128, tn0 = bn * 128;
    const int ty = tid >> 4, tx = tid & 15;
    float acc[8][8] = {};
    for (int kb = 0; kb < KTOT / 16; ++kb) {
        const int e = kb >> 4;
        const int rbase = (kb & 15) << 4;
        const int kglob = kb << 4;
        __syncthreads();
        #pragma unroll
        for (int h = 0; h < 2; ++h) {
            int f = tid + h * 256;
            int m = f >> 2, k4 = (f & 3) << 2;
            int t = tm0 + m;
            float4 a = *(const float4*)(xp + (size_t)t * RNK + rbase + k4);
            float wv = wts[(size_t)t * NEXP + e];
            As[k4 + 0][m] = a.x * wv; As[k4 + 1][m] = a.y * wv;
            As[k4 + 2][m] = a.z * wv; As[k4 + 3][m] = a.w * wv;
        }
        #pragma unroll
        for (int h = 0; h < 2; ++h) {
            int f = tid + h * 256;
            int kk = f >> 5, d4 = (f & 31) << 2;
            float4 b = *(const float4*)(E + (size_t)(kglob + kk) * DM + tn0 + d4);
            *(float4*)(&Bs[kk][d4]) = b;
        }
        __syncthreads();
        #pragma unroll
        for (int kk = 0; kk < 16; ++kk) {
            float4 a0 = *(const float4*)(&As[kk][ty * 8]);
            float4 a1 = *(const float4*)(&As[kk][ty * 8 + 4]);
            float4 b0 = *(const float4*)(&Bs[kk][tx * 8]);
            float4 b1 = *(const float4*)(&Bs[kk][tx * 8 + 4]);
            float av[8] = {a0.x, a0.y, a0.z, a0.w, a1.x, a1.y, a1.z, a1.w};
            float bw[8] = {b0.x, b0.y, b0.z, b0.w, b1.x, b1.y, b1.z, b1.w};
            #pragma unroll
            for (int i = 0; i < 8; ++i)
                #pragma unroll
                for (int j = 0; j < 8; ++j)
                    acc[i][j] = fmaf(av[i], bw[j], acc[i][j]);
        }
    }
    #pragma unroll
    for (int i = 0; i < 8; ++i) {
        int t = tm0 + ty * 8 + i;
        float* yrow = y + (size_t)t * DM + tn0 + tx * 8;
        *(float4*)yrow       = make_float4(acc[i][0], acc[i][1], acc[i][2], acc[i][3]);
        *(float4*)(yrow + 4) = make_float4(acc[i][4], acc[i][5], acc[i][6], acc[i][7]);
    }
}

__global__ __launch_bounds__(256) void k3_full(
    const float* __restrict__ Wd, const float* __restrict__ reflect_d,
    float* __restrict__ y, float* __restrict__ out_id)
{
    __shared__ float ys[4][DM];
    __shared__ float wds[64][17];
    const int tid = threadIdx.x;
    const int w = tid >> 6, lane = tid & 63;
    const int t = blockIdx.x * 4 + w;

    float4 yv[4];
    #pragma unroll
    for (int c = 0; c < 4; ++c) {
        yv[c] = *(const float4*)(y + (size_t)t * DM + lane * 16 + c * 4);
        *(float4*)(&ys[w][lane * 16 + c * 4]) = yv[c];
    }
    double s = 0.0;
    for (int kb = 0; kb < DM / 16; ++kb) {
        __syncthreads();
        {
            int row = tid >> 2, c4 = (tid & 3) << 2;
            float4 wv = *(const float4*)(Wd + (size_t)row * DM + kb * 16 + c4);
            wds[row][c4 + 0] = wv.x; wds[row][c4 + 1] = wv.y;
            wds[row][c4 + 2] = wv.z; wds[row][c4 + 3] = wv.w;
        }
        __syncthreads();
        #pragma unroll
        for (int i = 0; i < 16; ++i)
            s += (double)ys[w][kb * 16 + i] * (double)wds[lane][i];
    }
    int i0, i1;
    top2_64(s, lane, i0, i1);
    #pragma unroll
    for (int rr = 0; rr < 2; ++rr) {
        int idx = rr ? i1 : i0;
        const float* vrow = reflect_d + (size_t)idx * DM + lane * 16;
        float sv = 0.f, vn = 0.f;
        float4 vv[4];
        #pragma unroll
        for (int c = 0; c < 4; ++c) {
            vv[c] = *(const float4*)(vrow + c * 4);
            sv += vv[c].x * yv[c].x + vv[c].y * yv[c].y
                + vv[c].z * yv[c].z + vv[c].w * yv[c].w;
            vn += vv[c].x * vv[c].x + vv[c].y * vv[c].y
                + vv[c].z * vv[c].z + vv[c].w * vv[c].w;
        }
        #pragma unroll
        for (int m = 1; m < 64; m <<= 1) {
            sv += __shfl_xor(sv, m, 64);
            vn += __shfl_xor(vn, m, 64);
        }
        float coef = 2.0f * sv / (vn + 1e-8f);
        #pragma unroll
        for (int c = 0; c < 4; ++c) {
            yv[c].x -= coef * vv[c].x; yv[c].y -= coef * vv[c].y;
            yv[c].z -= coef * vv[c].z; yv[c].w -= coef * vv[c].w;
        }
    }
    #pragma unroll
    for (int c = 0; c < 4; ++c)
        *(float4*)(y + (size_t)t * DM + lane * 16 + c * 4) = yv[c];
    if (lane == 0) {
        out_id[(size_t)t * 2 + 0] = (float)i0;
        out_id[(size_t)t * 2 + 1] = (float)i1;
    }
}

extern "C" void kernel_launch(void* const* d_in, const int* in_sizes, int n_in,
                              void* d_out, int out_size, void* d_ws, size_t ws_size,
                              hipStream_t stream) {
    const float* x  = (const float*)d_in[0];
    const float* Wr = (const float*)d_in[1];
    const float* We = (const float*)d_in[2];
    const float* Wd = (const float*)d_in[3];
    const float* E  = (const float*)d_in[4];
    const float* rr = (const float*)d_in[5];
    const float* rd = (const float*)d_in[6];

    float* out    = (float*)d_out;
    float* y      = out + Y_OFF;
    float* out_ir = out + IR_OFF;
    float* out_w  = out + W_OFF;
    float* out_id = out + ID_OFF;

    if (ws_size >= WS_FULL) {
        char* p = (char*)d_ws;
        unsigned short* Ebt = (unsigned short*)p;  p += EBT_BYTES;
        float*          Xf  = (float*)p;           p += XF_BYTES;
        unsigned short* Xh  = (unsigned short*)p;  p += XH_BYTES;
        unsigned short* Xl  = (unsigned short*)p;  p += XH_BYTES;
        unsigned short* Gth = (unsigned short*)p;  p += GT_BYTES;
        unsigned short* Gtl = (unsigned short*)p;  p += GT_BYTES;
        float*          Sb  = (float*)p;           p += S_BYTES;   // unused
        double*         G64 = (double*)p;          p += G64_BYTES;
        double*         Srb = (double*)p;
        (void)Sb;

        prep<<<3072, 256, 0, stream>>>(x, Wr, E, Wd, Srb, Ebt, G64, Gth, Gtl);
        k1a<<<TOK / 4, 256, 0, stream>>>(Srb, x, We, rr, Xf,
                                         Xh, Xl, out_ir, out_w);
        k1b<<<TOK / 16, 512, 0, stream>>>(Xf, out_w, Gth, Gtl, G64,
                                          Xh, Xl, out_id);
        k2_fused<<<dim3(DM / 128, TOK / 128), 256, 0, stream>>>(Xh, Ebt, out_w, y);
        k3_post<<<TOK / 4, 256, 0, stream>>>(out_id, rd, y);
    } else {
        float* xprime = (float*)d_ws;
        k1_tokens<<<TOK / 4, 256, 0, stream>>>(x, Wr, We, rr, xprime,
                                               out_ir, out_w);
        k2_gemm<<<dim3(DM / 128, TOK / 128), 256, 0, stream>>>(xprime, out_w, E, y);
        k3_full<<<TOK / 4, 256, 0, stream>>>(Wd, rd, y, out_id);
    }
}

// Round 20
// 237.361 us; speedup vs baseline: 1.2192x; 1.2192x over previous
//
#include <hip/hip_runtime.h>
#include <cmath>

#define TOK   8192
#define RNK   256
#define NEXP  16
#define NREF  64
#define DM    1024
#define KTOT  4096

#define Y_OFF  0
#define IR_OFF (TOK*DM)
#define W_OFF  (IR_OFF + TOK*2)
#define ID_OFF (W_OFF + TOK*NEXP)

#define EBT_BYTES ((size_t)DM * KTOT * 2)         // 8 MB
#define XF_BYTES  ((size_t)TOK * RNK * 4)         // 8 MB
#define XH_BYTES  ((size_t)TOK * RNK * 2)         // 4 MB
#define GT_BYTES  ((size_t)NEXP * NREF * RNK * 2) // 512 KB (fragment order)
#define S_BYTES   ((size_t)TOK * NREF * 4)        // 2 MB (layout slot, unused)
#define G64_BYTES ((size_t)NREF * KTOT * 8)       // 2 MB
#define SR_BYTES  ((size_t)TOK * NREF * 8)        // 4 MB
#define WS_FULL   (EBT_BYTES + XF_BYTES + 2*XH_BYTES + 2*GT_BYTES + S_BYTES + G64_BYTES + SR_BYTES)

typedef __attribute__((ext_vector_type(8))) short short8;
typedef __attribute__((ext_vector_type(4))) float f32x4;
typedef const __attribute__((address_space(1))) void* gptr_t;
typedef __attribute__((address_space(3))) void* lptr_t;

__device__ inline unsigned short f2bf(float f) {    // RNE float->bf16
    unsigned int u = __float_as_uint(f);
    return (unsigned short)((u + 0x7fffu + ((u >> 16) & 1u)) >> 16);
}
__device__ inline float bf2f(unsigned short h) {
    return __uint_as_float(((unsigned int)h) << 16);
}
__device__ inline void split2(float v, unsigned short& h, unsigned short& l) {
    h = f2bf(v);
    l = f2bf(v - bf2f(h));
}
__device__ inline unsigned long long pack4(unsigned short a, unsigned short b,
                                           unsigned short c, unsigned short d) {
    return (unsigned long long)a | ((unsigned long long)b << 16)
         | ((unsigned long long)c << 32) | ((unsigned long long)d << 48);
}

// ---------- top-2 across a 64-lane wave, lax.top_k tie semantics ----------
__device__ inline void top2_64(double v, int idx, int& i0, int& i1) {
    double bv = v; int bi = idx;
    #pragma unroll
    for (int m = 1; m < 64; m <<= 1) {
        double ov = __shfl_xor(bv, m, 64);
        int    oi = __shfl_xor(bi, m, 64);
        if (ov > bv || (ov == bv && oi < bi)) { bv = ov; bi = oi; }
    }
    i0 = bi;
    double v2 = (idx == i0) ? -INFINITY : v;
    double bv2 = v2; int bi2 = idx;
    #pragma unroll
    for (int m = 1; m < 64; m <<= 1) {
        double ov = __shfl_xor(bv2, m, 64);
        int    oi = __shfl_xor(bi2, m, 64);
        if (ov > bv2 || (ov == bv2 && oi < bi2)) { bv2 = ov; bi2 = oi; }
    }
    i1 = bi2;
}

// ======== PREP: sr_fp64 (0..1023) | e_transpose (1024..2047) | g_fp64 ======
// g_fp64 now stores Gth/Gtl in MFMA *fragment order*:
//   idx(e,ks,nn,l,j) = (((e*8+ks)*4+nn)*64 + l)*8 + j
// so the s-body reads one contiguous 1KB line per wave-load (was a
// 16-row x 512B-stride gather -> half missed L2, r19 evidence).
__global__ __launch_bounds__(256) void prep(
    const float* __restrict__ x, const float* __restrict__ Wr,
    const float* __restrict__ E, const float* __restrict__ Wd,
    double* __restrict__ Sr, unsigned short* __restrict__ Ebt,
    double* __restrict__ G64t,
    unsigned short* __restrict__ Gth, unsigned short* __restrict__ Gtl)
{
    __shared__ __align__(16) float lds_raw[64 * 68];
    const int bid = blockIdx.x;
    const int tid = threadIdx.x;
    const int w = tid >> 6, n = tid & 63;

    if (bid < 1024) {
        // ---- sr_fp64: 8 tokens/block (2 per thread) ----
        float* wt2 = lds_raw;                // [64][68], wt2[n][d]
        const int t0 = bid * 8;
        double acc[2] = {0.0, 0.0};
        const float* xr0 = x + (size_t)(t0 + w * 2 + 0) * RNK;
        const float* xr1 = x + (size_t)(t0 + w * 2 + 1) * RNK;
        for (int d0 = 0; d0 < RNK; d0 += 64) {
            __syncthreads();
            #pragma unroll
            for (int rep = 0; rep < 4; ++rep) {
                int f = rep * 256 + tid;
                int nn = f >> 4, dgw = (f & 15) << 2;
                float4 v = *(const float4*)(Wr + (size_t)nn * RNK + d0 + dgw);
                *(float4*)&wt2[nn * 68 + dgw] = v;
            }
            __syncthreads();
            #pragma unroll
            for (int dg = 0; dg < 16; ++dg) {
                float4 e0 = *(const float4*)(xr0 + d0 + dg * 4);
                float4 e1 = *(const float4*)(xr1 + d0 + dg * 4);
                float4 w4 = *(const float4*)&wt2[n * 68 + dg * 4];
                #pragma unroll
                for (int j = 0; j < 4; ++j) {
                    double wv = (double)(&w4.x)[j];
                    acc[0] = fma((double)(&e0.x)[j], wv, acc[0]);
                    acc[1] = fma((double)(&e1.x)[j], wv, acc[1]);
                }
            }
        }
        #pragma unroll
        for (int i = 0; i < 2; ++i)
            Sr[(size_t)(t0 + w * 2 + i) * NREF + n] = acc[i];
    } else if (bid < 2048) {
        // ---- e_transpose ----
        const int id = bid - 1024;
        const int k0 = (id & 63) * 64, d0 = (id >> 6) * 64;
        #pragma unroll
        for (int rep = 0; rep < 4; ++rep) {
            int idx = rep * 256 + tid;
            int r = idx >> 4, c4 = (idx & 15) << 2;
            float4 v = *(const float4*)(E + (size_t)(k0 + r) * DM + d0 + c4);
            lds_raw[r * 68 + c4 + 0] = v.x; lds_raw[r * 68 + c4 + 1] = v.y;
            lds_raw[r * 68 + c4 + 2] = v.z; lds_raw[r * 68 + c4 + 3] = v.w;
        }
        __syncthreads();
        #pragma unroll
        for (int rep = 0; rep < 4; ++rep) {
            int idx = rep * 256 + tid;
            int dr = idx >> 4, kc4 = (idx & 15) << 2;
            *(unsigned long long*)&Ebt[(size_t)(d0 + dr) * KTOT + k0 + kc4] =
                pack4(f2bf(lds_raw[(kc4 + 0) * 68 + dr]),
                      f2bf(lds_raw[(kc4 + 1) * 68 + dr]),
                      f2bf(lds_raw[(kc4 + 2) * 68 + dr]),
                      f2bf(lds_raw[(kc4 + 3) * 68 + dr]));
        }
    } else {
        // ---- g_fp64: 4 k-rows/block (1 per wave) ----
        float* wt2 = lds_raw;                // [64][68], wt2[n][d]
        const int k = (bid - 2048) * 4 + w;
        double acc = 0.0;
        const float* erow = E + (size_t)k * DM;
        for (int d0 = 0; d0 < DM; d0 += 64) {
            __syncthreads();
            #pragma unroll
            for (int rep = 0; rep < 4; ++rep) {
                int f = rep * 256 + tid;
                int nn = f >> 4, dgw = (f & 15) << 2;
                float4 v = *(const float4*)(Wd + (size_t)nn * DM + d0 + dgw);
                *(float4*)&wt2[nn * 68 + dgw] = v;
            }
            __syncthreads();
            #pragma unroll
            for (int dg = 0; dg < 16; ++dg) {
                float4 e0 = *(const float4*)(erow + d0 + dg * 4);
                float4 w4 = *(const float4*)&wt2[n * 68 + dg * 4];
                #pragma unroll
                for (int j = 0; j < 4; ++j)
                    acc = fma((double)(&e0.x)[j], (double)(&w4.x)[j], acc);
            }
        }
        G64t[(size_t)n * KTOT + k] = acc;
        float gf = (float)acc;
        unsigned short h, lo;
        split2(gf, h, lo);
        // fragment-order store (same values, relocated)
        const int e = k >> 8, r = k & 255;
        const int ks = r >> 5, q = (r >> 3) & 3, j = r & 7;
        const int nn = n >> 4;
        const int lfrag = (n & 15) | (q << 4);
        size_t fidx = ((((size_t)(e * 8 + ks) * 4 + nn) * 64) + lfrag) * 8 + j;
        Gth[fidx] = h;
        Gtl[fidx] = lo;
    }
}

// ======== K1S (8 waves): k1 + s_mfma + gap-gated refine (r18 structure) ====
// Only change vs r18: s-body G reads use fragment-order layout (coalesced).
__global__ __launch_bounds__(512, 4) void k1s(
    const double* __restrict__ Sr, const float* __restrict__ x,
    const float* __restrict__ We, const float* __restrict__ reflect_r,
    const unsigned short* __restrict__ Gth, const unsigned short* __restrict__ Gtl,
    const double* __restrict__ G64t,
    float* __restrict__ xprime,
    unsigned short* __restrict__ Xh, unsigned short* __restrict__ Xl,
    float* __restrict__ out_ir, float* __restrict__ out_w,
    float* __restrict__ out_id)
{
    __shared__ __align__(16) char smem_u[16640];   // we_lds(16.6K) ∪ red(16K)
    __shared__ float xs[16][260];                  // 16.6 KB
    __shared__ float wsh[16][16];                  // 1 KB
    __shared__ float sfin[16][64];                 // 4 KB
    float* we_lds = (float*)smem_u;
    float* red    = (float*)smem_u;

    const int tid = threadIdx.x;
    const int w = tid >> 6, lane = tid & 63;   // w = 0..7
    const int t0 = blockIdx.x * 16;

    #pragma unroll
    for (int rep = 0; rep < 2; ++rep) {
        int f = rep * 512 + tid;
        int row = f >> 6, c4 = (f & 63) << 2;
        float4 v = *(const float4*)(We + (size_t)row * RNK + c4);
        *(float4*)&we_lds[row * 260 + c4] = v;
    }
    __syncthreads();

    for (int it = 0; it < 2; ++it) {
        const int tloc = it * 8 + w;
        const int t = t0 + tloc;

        float4 xv = *(const float4*)(x + (size_t)t * RNK + lane * 4);
        double s = Sr[(size_t)t * NREF + lane];
        int i0, i1;
        top2_64(s, lane, i0, i1);

        #pragma unroll
        for (int rr = 0; rr < 2; ++rr) {
            int idx = rr ? i1 : i0;
            float4 vv = *(const float4*)(reflect_r + (size_t)idx * RNK + lane * 4);
            float sv = vv.x * xv.x + vv.y * xv.y + vv.z * xv.z + vv.w * xv.w;
            float vn = vv.x * vv.x + vv.y * vv.y + vv.z * vv.z + vv.w * vv.w;
            #pragma unroll
            for (int m = 1; m < 64; m <<= 1) {
                sv += __shfl_xor(sv, m, 64);
                vn += __shfl_xor(vn, m, 64);
            }
            float coef = 2.0f * sv / (vn + 1e-8f);
            xv.x -= coef * vv.x; xv.y -= coef * vv.y;
            xv.z -= coef * vv.z; xv.w -= coef * vv.w;
        }

        *(float4*)&xs[tloc][lane * 4] = xv;
        *(float4*)(xprime + (size_t)t * RNK + lane * 4) = xv;

        const int n16 = lane & 15;
        double se = 0.0;
        {
            const float* werow = &we_lds[n16 * 260];
            #pragma unroll 8
            for (int r4 = 0; r4 < RNK / 4; ++r4) {
                float4 xr = *(const float4*)(&xs[tloc][r4 * 4]);
                float4 wf = *(const float4*)(werow + r4 * 4);
                se += (double)xr.x * wf.x + (double)xr.y * wf.y
                    + (double)xr.z * wf.z + (double)xr.w * wf.w;
            }
        }
        float sef = (float)se;
        float mx = sef;
        #pragma unroll
        for (int m = 1; m < 16; m <<= 1) mx = fmaxf(mx, __shfl_xor(mx, m, 64));
        float ex = expf(sef - mx);
        float sm = ex;
        #pragma unroll
        for (int m = 1; m < 16; m <<= 1) sm += __shfl_xor(sm, m, 64);
        float wgt = ex / sm;

        if (lane < NEXP) {
            out_w[(size_t)t * NEXP + lane] = wgt;
            wsh[tloc][lane] = wgt;
        }
        if (lane == 0) {
            out_ir[(size_t)t * 2 + 0] = (float)i0;
            out_ir[(size_t)t * 2 + 1] = (float)i1;
        }

        unsigned short hx, lx, hy, ly, hz, lz, hw, lw;
        split2(xv.x, hx, lx); split2(xv.y, hy, ly);
        split2(xv.z, hz, lz); split2(xv.w, hw, lw);
        *(unsigned long long*)&Xh[(size_t)t * RNK + lane * 4] = pack4(hx, hy, hz, hw);
        *(unsigned long long*)&Xl[(size_t)t * RNK + lane * 4] = pack4(lx, ly, lz, lw);
    }
    __syncthreads();   // we_lds dead; Xh/Xl visible block-wide; xs/wsh ready

    // ---- s-body: 8 waves x 2 experts; coalesced fragment-order G reads ----
    const int l = lane;
    short8 ah[8], al[8];
    {
        const size_t abase = (size_t)(t0 + (l & 15)) * RNK + (l >> 4) * 8;
        #pragma unroll
        for (int ks = 0; ks < 8; ++ks) {
            ah[ks] = *(const short8*)&Xh[abase + ks * 32];
            al[ks] = *(const short8*)&Xl[abase + ks * 32];
        }
    }

    f32x4 Sacc[4] = {};
    #pragma unroll
    for (int ei = 0; ei < 2; ++ei) {
        const int e = w * 2 + ei;
        f32x4 acc[4] = {};
        #pragma unroll
        for (int ks = 0; ks < 8; ++ks) {
            #pragma unroll
            for (int nn = 0; nn < 4; ++nn) {
                size_t gbase = ((((size_t)(e * 8 + ks) * 4 + nn) * 64) + l) * 8;
                short8 bh = *(const short8*)&Gth[gbase];
                short8 bl = *(const short8*)&Gtl[gbase];
                acc[nn] = __builtin_amdgcn_mfma_f32_16x16x32_bf16(al[ks], bh, acc[nn], 0, 0, 0);
                acc[nn] = __builtin_amdgcn_mfma_f32_16x16x32_bf16(ah[ks], bl, acc[nn], 0, 0, 0);
                acc[nn] = __builtin_amdgcn_mfma_f32_16x16x32_bf16(ah[ks], bh, acc[nn], 0, 0, 0);
            }
        }
        #pragma unroll
        for (int j = 0; j < 4; ++j) {
            float wv = wsh[(l >> 4) * 4 + j][e];
            #pragma unroll
            for (int nn = 0; nn < 4; ++nn) Sacc[nn][j] += wv * acc[nn][j];
        }
    }
    // two-phase reduction into red[4][16][64]
    if (w < 4) {
        #pragma unroll
        for (int nn = 0; nn < 4; ++nn)
            #pragma unroll
            for (int j = 0; j < 4; ++j)
                red[(w * 16 + (l >> 4) * 4 + j) * 64 + nn * 16 + (l & 15)] = Sacc[nn][j];
    }
    __syncthreads();
    if (w >= 4) {
        #pragma unroll
        for (int nn = 0; nn < 4; ++nn)
            #pragma unroll
            for (int j = 0; j < 4; ++j)
                red[((w - 4) * 16 + (l >> 4) * 4 + j) * 64 + nn * 16 + (l & 15)] += Sacc[nn][j];
    }
    __syncthreads();
    for (int i = tid; i < 16 * 64; i += 512) {
        int tt = i >> 6, nn = i & 63;
        float sv = red[(0 * 16 + tt) * 64 + nn] + red[(1 * 16 + tt) * 64 + nn]
                 + red[(2 * 16 + tt) * 64 + nn] + red[(3 * 16 + tt) * 64 + nn];
        sfin[tt][nn] = sv;
    }
    __syncthreads();

    // ---- gap-gated refine: wave w handles tokens 2w, 2w+1 ----
    const float TAU = 1e-3f;   // >> S error (~3e-5)
    for (int ti = 0; ti < 2; ++ti) {
        const int tloc = w * 2 + ti;
        const int t = t0 + tloc;

        float cur = sfin[tloc][lane];
        int cand[4];
        float sval[4];
        #pragma unroll
        for (int c = 0; c < 4; ++c) {
            float bv = cur; int bi = lane;
            #pragma unroll
            for (int m = 1; m < 64; m <<= 1) {
                float ov = __shfl_xor(bv, m, 64);
                int   oi = __shfl_xor(bi, m, 64);
                if (ov > bv || (ov == bv && oi < bi)) { bv = ov; bi = oi; }
            }
            cand[c] = bi; sval[c] = bv;
            if (lane == bi) cur = -INFINITY;
        }

        int si0, si1;
        if (sval[0] - sval[1] > TAU && sval[1] - sval[2] > TAU) {
            si0 = cand[0]; si1 = cand[1];
        } else {
            double rs[4];
            #pragma unroll
            for (int c = 0; c < 4; ++c) {
                const double* grow = G64t + (size_t)cand[c] * KTOT;
                double acc = 0.0;
                #pragma unroll 4
                for (int i = 0; i < 64; ++i) {
                    int k = i * 64 + lane;
                    double a = (double)wsh[tloc][k >> 8] * (double)xs[tloc][k & 255];
                    acc = fma(a, grow[k], acc);
                }
                #pragma unroll
                for (int m = 1; m < 64; m <<= 1) acc += __shfl_xor(acc, m, 64);
                rs[c] = acc;
            }
            int b0 = 0;
            #pragma unroll
            for (int c = 1; c < 4; ++c)
                if (rs[c] > rs[b0] || (rs[c] == rs[b0] && cand[c] < cand[b0])) b0 = c;
            int b1 = (b0 == 0) ? 1 : 0;
            #pragma unroll
            for (int c = 0; c < 4; ++c) {
                if (c == b0) continue;
                if (rs[c] > rs[b1] || (rs[c] == rs[b1] && cand[c] < cand[b1])) b1 = c;
            }
            si0 = cand[b0]; si1 = cand[b1];
        }
        if (lane == 0) {
            out_id[(size_t)t * 2 + 0] = (float)si0;
            out_id[(size_t)t * 2 + 1] = (float)si1;
        }
    }
}

// ---------- K2 fused (round-8 structure, STANDALONE) ----------------------
__global__ __launch_bounds__(256) void k2_fused(
    const unsigned short* __restrict__ Xh,
    const unsigned short* __restrict__ Ebt,
    const float* __restrict__ wts,
    float* __restrict__ y)
{
    __shared__ unsigned short As[128 * 32];
    __shared__ unsigned short Bs[128 * 32];
    __shared__ float wt[NEXP * 132];
    const int tid = threadIdx.x;
    const int l = tid & 63, w = tid >> 6;
    const int wr = w >> 1, wc = w & 1;
    const int tm0 = blockIdx.y * 128, n0 = blockIdx.x * 128;
    const int lrow = l >> 2, s = l & 3, g = l >> 4;

    #pragma unroll
    for (int rep = 0; rep < 8; ++rep) {
        int f = rep * 256 + tid;
        int row = f >> 4, e = f & 15;
        wt[e * 132 + row] = wts[(size_t)(tm0 + row) * NEXP + e];
    }

    f32x4 acc[4][4] = {};

    for (int e = 0; e < NEXP; ++e) {
        f32x4 acc_e[4][4] = {};
        for (int kb8 = 0; kb8 < 8; ++kb8) {
            const int kb = e * 8 + kb8;
            __syncthreads();
            #pragma unroll
            for (int i = 0; i < 2; ++i) {
                int row = w * 32 + i * 16 + lrow;
                int sw = ((s ^ ((row >> 1) & 3)) << 4);
                const char* ga = (const char*)Xh
                    + ((size_t)(tm0 + row) * RNK + kb8 * 32) * 2 + sw;
                __builtin_amdgcn_global_load_lds((gptr_t)ga,
                    (lptr_t)&As[(w * 32 + i * 16) * 32], 16, 0, 0);
                const char* gb = (const char*)Ebt
                    + ((size_t)(n0 + row) * KTOT + kb * 32) * 2 + sw;
                __builtin_amdgcn_global_load_lds((gptr_t)gb,
                    (lptr_t)&Bs[(w * 32 + i * 16) * 32], 16, 0, 0);
            }
            __syncthreads();

            short8 af[4], bv[4];
            #pragma unroll
            for (int m = 0; m < 4; ++m) {
                int row = wr * 64 + m * 16 + (l & 15);
                af[m] = *(const short8*)&As[row * 32 + ((g ^ ((row >> 1) & 3)) << 3)];
            }
            #pragma unroll
            for (int nn = 0; nn < 4; ++nn) {
                int row = wc * 64 + nn * 16 + (l & 15);
                bv[nn] = *(const short8*)&Bs[row * 32 + ((g ^ ((row >> 1) & 3)) << 3)];
            }
            #pragma unroll
            for (int m = 0; m < 4; ++m)
                #pragma unroll
                for (int nn = 0; nn < 4; ++nn)
                    acc_e[m][nn] = __builtin_amdgcn_mfma_f32_16x16x32_bf16(
                        af[m], bv[nn], acc_e[m][nn], 0, 0, 0);
        }
        #pragma unroll
        for (int m = 0; m < 4; ++m) {
            int rowb = wr * 64 + m * 16 + (l >> 4) * 4;
            float4 wm = *(const float4*)&wt[e * 132 + rowb];
            #pragma unroll
            for (int nn = 0; nn < 4; ++nn) {
                #pragma unroll
                for (int j = 0; j < 4; ++j)
                    acc[m][nn][j] += (&wm.x)[j] * acc_e[m][nn][j];
            }
        }
    }

    #pragma unroll
    for (int m = 0; m < 4; ++m) {
        int rbase = tm0 + wr * 64 + m * 16 + (l >> 4) * 4;
        #pragma unroll
        for (int nn = 0; nn < 4; ++nn) {
            int c = n0 + wc * 64 + nn * 16 + (l & 15);
            #pragma unroll
            for (int j = 0; j < 4; ++j)
                y[(size_t)(rbase + j) * DM + c] = acc[m][nn][j];
        }
    }
}

// ---------- K3: read refined indices -> 2 reflections on y (in place) -----
__global__ __launch_bounds__(256) void k3_post(
    const float* __restrict__ out_id, const float* __restrict__ reflect_d,
    float* __restrict__ y)
{
    const int tid = threadIdx.x;
    const int w = tid >> 6, lane = tid & 63;
    const int t = blockIdx.x * 4 + w;

    float4 yv[4];
    #pragma unroll
    for (int c = 0; c < 4; ++c)
        yv[c] = *(const float4*)(y + (size_t)t * DM + lane * 16 + c * 4);

    const int i0 = (int)out_id[(size_t)t * 2 + 0];
    const int i1 = (int)out_id[(size_t)t * 2 + 1];

    #pragma unroll
    for (int rr = 0; rr < 2; ++rr) {
        int idx = rr ? i1 : i0;
        const float* vrow = reflect_d + (size_t)idx * DM + lane * 16;
        float sv = 0.f, vn = 0.f;
        float4 vv[4];
        #pragma unroll
        for (int c = 0; c < 4; ++c) {
            vv[c] = *(const float4*)(vrow + c * 4);
            sv += vv[c].x * yv[c].x + vv[c].y * yv[c].y
                + vv[c].z * yv[c].z + vv[c].w * yv[c].w;
            vn += vv[c].x * vv[c].x + vv[c].y * vv[c].y
                + vv[c].z * vv[c].z + vv[c].w * vv[c].w;
        }
        #pragma unroll
        for (int m = 1; m < 64; m <<= 1) {
            sv += __shfl_xor(sv, m, 64);
            vn += __shfl_xor(vn, m, 64);
        }
        float coef = 2.0f * sv / (vn + 1e-8f);
        #pragma unroll
        for (int c = 0; c < 4; ++c) {
            yv[c].x -= coef * vv[c].x; yv[c].y -= coef * vv[c].y;
            yv[c].z -= coef * vv[c].z; yv[c].w -= coef * vv[c].w;
        }
    }
    #pragma unroll
    for (int c = 0; c < 4; ++c)
        *(float4*)(y + (size_t)t * DM + lane * 16 + c * 4) = yv[c];
}

// ================= fallback path (ws too small), unchanged =================
__global__ __launch_bounds__(256) void k1_tokens(
    const float* __restrict__ x, const float* __restrict__ Wr,
    const float* __restrict__ We, const float* __restrict__ reflect_r,
    float* __restrict__ xprime, float* __restrict__ out_ir,
    float* __restrict__ out_w)
{
    __shared__ float xs[4][RNK];
    const int tid = threadIdx.x;
    const int w = tid >> 6, lane = tid & 63;
    const int t = blockIdx.x * 4 + w;

    float4 xv = *(const float4*)(x + (size_t)t * RNK + lane * 4);
    *(float4*)(&xs[w][lane * 4]) = xv;
    __syncthreads();

    double s = 0.0;
    {
        const float* wrow = Wr + (size_t)lane * RNK;
        for (int r4 = 0; r4 < RNK / 4; ++r4) {
            float4 xr = *(const float4*)(&xs[w][r4 * 4]);
            float4 wr = *(const float4*)(wrow + r4 * 4);
            s += (double)xr.x * wr.x + (double)xr.y * wr.y
               + (double)xr.z * wr.z + (double)xr.w * wr.w;
        }
    }
    int i0, i1;
    top2_64(s, lane, i0, i1);

    #pragma unroll
    for (int rr = 0; rr < 2; ++rr) {
        int idx = rr ? i1 : i0;
        float4 vv = *(const float4*)(reflect_r + (size_t)idx * RNK + lane * 4);
        float sv = vv.x * xv.x + vv.y * xv.y + vv.z * xv.z + vv.w * xv.w;
        float vn = vv.x * vv.x + vv.y * vv.y + vv.z * vv.z + vv.w * vv.w;
        #pragma unroll
        for (int m = 1; m < 64; m <<= 1) {
            sv += __shfl_xor(sv, m, 64);
            vn += __shfl_xor(vn, m, 64);
        }
        float coef = 2.0f * sv / (vn + 1e-8f);
        xv.x -= coef * vv.x; xv.y -= coef * vv.y;
        xv.z -= coef * vv.z; xv.w -= coef * vv.w;
    }
    __syncthreads();
    *(float4*)(&xs[w][lane * 4]) = xv;
    __syncthreads();

    *(float4*)(xprime + (size_t)t * RNK + lane * 4) = xv;

    const int n = lane & 15;
    double se = 0.0;
    {
        const float* werow = We + (size_t)n * RNK;
        for (int r4 = 0; r4 < RNK / 4; ++r4) {
            float4 xr = *(const float4*)(&xs[w][r4 * 4]);
            float4 wf = *(const float4*)(werow + r4 * 4);
            se += (double)xr.x * wf.x + (double)xr.y * wf.y
                + (double)xr.z * wf.z + (double)xr.w * wf.w;
        }
    }
    float sef = (float)se;
    float mx = sef;
    #pragma unroll
    for (int m = 1; m < 16; m <<= 1) mx = fmaxf(mx, __shfl_xor(mx, m, 64));
    float ex = expf(sef - mx);
    float sm = ex;
    #pragma unroll
    for (int m = 1; m < 16; m <<= 1) sm += __shfl_xor(sm, m, 64);
    float wgt = ex / sm;

    if (lane < NEXP) out_w[(size_t)t * NEXP + lane] = wgt;
    if (lane == 0) {
        out_ir[(size_t)t * 2 + 0] = (float)i0;
        out_ir[(size_t)t * 2 + 1] = (float)i1;
    }
}

__global__ __launch_bounds__(256) void k2_gemm(
    const float* __restrict__ xp, const float* __restrict__ wts,
    const float* __restrict__ E, float* __restrict__ y)
{
    __shared__ float As[16][132];
    __shared__ float Bs[16][132];
    const int tid = threadIdx.x;
    const int bn = blockIdx.x, bm = blockIdx.y;
    const int tm0 = bm * 128, tn0 = bn * 128;
    const int ty = tid >> 4, tx = tid & 15;
    float acc[8][8] = {};
    for (int kb = 0; kb < KTOT / 16; ++kb) {
        const int e = kb >> 4;
        const int rbase = (kb & 15) << 4;
        const int kglob = kb << 4;
        __syncthreads();
        #pragma unroll
        for (int h = 0; h < 2; ++h) {
            int f = tid + h * 256;
            int m = f >> 2, k4 = (f & 3) << 2;
            int t = tm0 + m;
            float4 a = *(const float4*)(xp + (size_t)t * RNK + rbase + k4);
            float wv = wts[(size_t)t * NEXP + e];
            As[k4 + 0][m] = a.x * wv; As[k4 + 1][m] = a.y * wv;
            As[k4 + 2][m] = a.z * wv; As[k4 + 3][m] = a.w * wv;
        }
        #pragma unroll
        for (int h = 0; h < 2; ++h) {
            int f = tid + h * 256;
            int kk = f >> 5, d4 = (f & 31) << 2;
            float4 b = *(const float4*)(E + (size_t)(kglob + kk) * DM + tn0 + d4);
            *(float4*)(&Bs[kk][d4]) = b;
        }
        __syncthreads();
        #pragma unroll
        for (int kk = 0; kk < 16; ++kk) {
            float4 a0 = *(const float4*)(&As[kk][ty * 8]);
            float4 a1 = *(const float4*)(&As[kk][ty * 8 + 4]);
            float4 b0 = *(const float4*)(&Bs[kk][tx * 8]);
            float4 b1 = *(const float4*)(&Bs[kk][tx * 8 + 4]);
            float av[8] = {a0.x, a0.y, a0.z, a0.w, a1.x, a1.y, a1.z, a1.w};
            float bw[8] = {b0.x, b0.y, b0.z, b0.w, b1.x, b1.y, b1.z, b1.w};
            #pragma unroll
            for (int i = 0; i < 8; ++i)
                #pragma unroll
                for (int j = 0; j < 8; ++j)
                    acc[i][j] = fmaf(av[i], bw[j], acc[i][j]);
        }
    }
    #pragma unroll
    for (int i = 0; i < 8; ++i) {
        int t = tm0 + ty * 8 + i;
        float* yrow = y + (size_t)t * DM + tn0 + tx * 8;
        *(float4*)yrow       = make_float4(acc[i][0], acc[i][1], acc[i][2], acc[i][3]);
        *(float4*)(yrow + 4) = make_float4(acc[i][4], acc[i][5], acc[i][6], acc[i][7]);
    }
}

__global__ __launch_bounds__(256) void k3_full(
    const float* __restrict__ Wd, const float* __restrict__ reflect_d,
    float* __restrict__ y, float* __restrict__ out_id)
{
    __shared__ float ys[4][DM];
    __shared__ float wds[64][17];
    const int tid = threadIdx.x;
    const int w = tid >> 6, lane = tid & 63;
    const int t = blockIdx.x * 4 + w;

    float4 yv[4];
    #pragma unroll
    for (int c = 0; c < 4; ++c) {
        yv[c] = *(const float4*)(y + (size_t)t * DM + lane * 16 + c * 4);
        *(float4*)(&ys[w][lane * 16 + c * 4]) = yv[c];
    }
    double s = 0.0;
    for (int kb = 0; kb < DM / 16; ++kb) {
        __syncthreads();
        {
            int row = tid >> 2, c4 = (tid & 3) << 2;
            float4 wv = *(const float4*)(Wd + (size_t)row * DM + kb * 16 + c4);
            wds[row][c4 + 0] = wv.x; wds[row][c4 + 1] = wv.y;
            wds[row][c4 + 2] = wv.z; wds[row][c4 + 3] = wv.w;
        }
        __syncthreads();
        #pragma unroll
        for (int i = 0; i < 16; ++i)
            s += (double)ys[w][kb * 16 + i] * (double)wds[lane][i];
    }
    int i0, i1;
    top2_64(s, lane, i0, i1);
    #pragma unroll
    for (int rr = 0; rr < 2; ++rr) {
        int idx = rr ? i1 : i0;
        const float* vrow = reflect_d + (size_t)idx * DM + lane * 16;
        float sv = 0.f, vn = 0.f;
        float4 vv[4];
        #pragma unroll
        for (int c = 0; c < 4; ++c) {
            vv[c] = *(const float4*)(vrow + c * 4);
            sv += vv[c].x * yv[c].x + vv[c].y * yv[c].y
                + vv[c].z * yv[c].z + vv[c].w * yv[c].w;
            vn += vv[c].x * vv[c].x + vv[c].y * vv[c].y
                + vv[c].z * vv[c].z + vv[c].w * vv[c].w;
        }
        #pragma unroll
        for (int m = 1; m < 64; m <<= 1) {
            sv += __shfl_xor(sv, m, 64);
            vn += __shfl_xor(vn, m, 64);
        }
        float coef = 2.0f * sv / (vn + 1e-8f);
        #pragma unroll
        for (int c = 0; c < 4; ++c) {
            yv[c].x -= coef * vv[c].x; yv[c].y -= coef * vv[c].y;
            yv[c].z -= coef * vv[c].z; yv[c].w -= coef * vv[c].w;
        }
    }
    #pragma unroll
    for (int c = 0; c < 4; ++c)
        *(float4*)(y + (size_t)t * DM + lane * 16 + c * 4) = yv[c];
    if (lane == 0) {
        out_id[(size_t)t * 2 + 0] = (float)i0;
        out_id[(size_t)t * 2 + 1] = (float)i1;
    }
}

extern "C" void kernel_launch(void* const* d_in, const int* in_sizes, int n_in,
                              void* d_out, int out_size, void* d_ws, size_t ws_size,
                              hipStream_t stream) {
    const float* x  = (const float*)d_in[0];
    const float* Wr = (const float*)d_in[1];
    const float* We = (const float*)d_in[2];
    const float* Wd = (const float*)d_in[3];
    const float* E  = (const float*)d_in[4];
    const float* rr = (const float*)d_in[5];
    const float* rd = (const float*)d_in[6];

    float* out    = (float*)d_out;
    float* y      = out + Y_OFF;
    float* out_ir = out + IR_OFF;
    float* out_w  = out + W_OFF;
    float* out_id = out + ID_OFF;

    if (ws_size >= WS_FULL) {
        char* p = (char*)d_ws;
        unsigned short* Ebt = (unsigned short*)p;  p += EBT_BYTES;
        float*          Xf  = (float*)p;           p += XF_BYTES;
        unsigned short* Xh  = (unsigned short*)p;  p += XH_BYTES;
        unsigned short* Xl  = (unsigned short*)p;  p += XH_BYTES;
        unsigned short* Gth = (unsigned short*)p;  p += GT_BYTES;
        unsigned short* Gtl = (unsigned short*)p;  p += GT_BYTES;
        float*          Sb  = (float*)p;           p += S_BYTES;   // unused
        double*         G64 = (double*)p;          p += G64_BYTES;
        double*         Srb = (double*)p;
        (void)Sb;

        prep<<<3072, 256, 0, stream>>>(x, Wr, E, Wd, Srb, Ebt, G64, Gth, Gtl);
        k1s<<<TOK / 16, 512, 0, stream>>>(Srb, x, We, rr, Gth, Gtl, G64, Xf,
                                          Xh, Xl, out_ir, out_w, out_id);
        k2_fused<<<dim3(DM / 128, TOK / 128), 256, 0, stream>>>(Xh, Ebt, out_w, y);
        k3_post<<<TOK / 4, 256, 0, stream>>>(out_id, rd, y);
    } else {
        float* xprime = (float*)d_ws;
        k1_tokens<<<TOK / 4, 256, 0, stream>>>(x, Wr, We, rr, xprime,
                                               out_ir, out_w);
        k2_gemm<<<dim3(DM / 128, TOK / 128), 256, 0, stream>>>(xprime, out_w, E, y);
        k3_full<<<TOK / 4, 256, 0, stream>>>(Wd, rd, y, out_id);
    }
}